// Round 1
// baseline (951.068 us; speedup 1.0000x reference)
//
#include <hip/hip_runtime.h>
#include <hip/hip_bf16.h>

#define NB 32
#define NC 256
#define NHW 4096                 // 64*64
#define NN (NB*NHW)              // 131072 rows
#define NK 1024                  // codes
#define NUMEL ((size_t)NN*NC)    // 33554432
#define NBLK (NN/64)             // 2048 blocks

// ---------------- e_norm[k] = sum_c emb[k,c]^2 ----------------
__global__ void vq_enorm(const float* __restrict__ emb, float* __restrict__ enorm) {
    int k = blockIdx.x * 256 + threadIdx.x;
    if (k >= NK) return;
    const float4* row = (const float4*)(emb + (size_t)k * NC);
    float s = 0.f;
#pragma unroll
    for (int i = 0; i < NC/4; ++i) {
        float4 v = row[i];
        s = fmaf(v.x, v.x, fmaf(v.y, v.y, fmaf(v.z, v.z, fmaf(v.w, v.w, s))));
    }
    enorm[k] = s;
}

// ---------------- main: distances + argmin + gather + loss ----------------
// block = 256 threads, owns 64 rows (one b, 64 consecutive hw)
__global__ __launch_bounds__(256, 2)
void vq_main(const float* __restrict__ x, const float* __restrict__ emb,
             const float* __restrict__ enorm,
             float* __restrict__ out, float* __restrict__ partials) {
    __shared__ float Xs[256][64];   // [d][row]  64 KiB, staged once
    __shared__ float Es[64][64];    // [d][code] 16 KiB, restaged per chunk; reused for reductions

    const int tid = threadIdx.x;
    const int blk = blockIdx.x;
    const int b   = blk >> 6;            // 64 tiles per batch image
    const int hw0 = (blk & 63) << 6;

    // stage X tile: Xs[d][r] = x[b, d, hw0+r]   (coalesced 256B per d-group)
    {
        const int r4 = (tid & 15) << 2;
        const int d0 = tid >> 4;
#pragma unroll
        for (int it = 0; it < 16; ++it) {
            const int d = d0 + it * 16;
            const float4 v = *(const float4*)(x + ((size_t)(b*NC + d) * NHW) + hw0 + r4);
            *(float4*)&Xs[d][r4] = v;
        }
    }

    const int ty = tid >> 4;   // row group: rows ty*4 .. ty*4+3
    const int tx = tid & 15;   // code group: codes tx*4 .. tx*4+3 (per chunk)

    float bestv[4]; int besti[4];
#pragma unroll
    for (int i = 0; i < 4; ++i) { bestv[i] = 3.4e38f; besti[i] = 0; }

    for (int kc = 0; kc < 16; ++kc) {
        const int k0 = kc << 6;
        float acc[4][4];
#pragma unroll
        for (int i = 0; i < 4; ++i)
#pragma unroll
            for (int j = 0; j < 4; ++j) acc[i][j] = 0.f;

        for (int ds = 0; ds < 4; ++ds) {
            __syncthreads();   // protect Es from previous readers (also fences Xs stage on first pass)
            // stage Es[dl][k] = emb[k0+k][ds*64+dl]
            {
                const int k  = tid >> 2;
                const int dq = tid & 3;
#pragma unroll
                for (int j = 0; j < 4; ++j) {
                    const int dl = (dq << 2) + (j << 4);
                    const float4 ev = *(const float4*)(emb + (size_t)(k0 + k) * NC + (ds << 6) + dl);
                    Es[dl + 0][k] = ev.x;
                    Es[dl + 1][k] = ev.y;
                    Es[dl + 2][k] = ev.z;
                    Es[dl + 3][k] = ev.w;
                }
            }
            __syncthreads();

#pragma unroll 8
            for (int dl = 0; dl < 64; ++dl) {
                const float4 xf = *(const float4*)&Xs[(ds << 6) + dl][ty << 2];
                const float4 ef = *(const float4*)&Es[dl][tx << 2];
                const float xa[4] = {xf.x, xf.y, xf.z, xf.w};
                const float ea[4] = {ef.x, ef.y, ef.z, ef.w};
#pragma unroll
                for (int i = 0; i < 4; ++i)
#pragma unroll
                    for (int j = 0; j < 4; ++j)
                        acc[i][j] = fmaf(xa[i], ea[j], acc[i][j]);
            }
        }

        // chunk epilogue: dist = ||e||^2 - 2 x.e   (||x||^2 dropped: constant per row)
#pragma unroll
        for (int j = 0; j < 4; ++j) {
            const int k = k0 + (tx << 2) + j;
            const float en = enorm[k];
#pragma unroll
            for (int i = 0; i < 4; ++i) {
                const float dist = fmaf(-2.f, acc[i][j], en);
                if (dist < bestv[i]) { bestv[i] = dist; besti[i] = k; }
            }
        }
    }

    // ---- cross-thread argmin per row (16 tx threads per row) ----
    __syncthreads();
    float* rv   = &Es[0][0];          // 1024 floats
    int*   ri   = (int*)&Es[16][0];   // 1024 ints
    int*   widx = (int*)&Es[32][0];   // 64 ints
    float* wsum = &Es[33][0];         // 4 floats
#pragma unroll
    for (int i = 0; i < 4; ++i) {
        const int r = (ty << 2) + i;
        rv[r * 16 + tx] = bestv[i];
        ri[r * 16 + tx] = besti[i];
    }
    __syncthreads();
    if (tid < 64) {
        const int r = tid;
        float bv = rv[r * 16]; int bi = ri[r * 16];
#pragma unroll
        for (int t = 1; t < 16; ++t) {
            const float v = rv[r * 16 + t]; const int ii = ri[r * 16 + t];
            if (v < bv || (v == bv && ii < bi)) { bv = v; bi = ii; }
        }
        widx[r] = bi;
    }
    __syncthreads();

    // ---- gather + output write + loss (x still resident in Xs) ----
    float lloss = 0.f;
    {
        const int r  = tid & 63;
        const int cg = tid >> 6;               // 0..3 -> c in [cg*64, cg*64+64)
        const float* erow = emb + (size_t)widx[r] * NC;
#pragma unroll 4
        for (int cc = 0; cc < 16; ++cc) {
            const int c4 = (cg << 6) + (cc << 2);
            const float4 ev = *(const float4*)(erow + c4);
            const float va[4] = {ev.x, ev.y, ev.z, ev.w};
#pragma unroll
            for (int q = 0; q < 4; ++q) {
                const int c = c4 + q;
                const float d = va[q] - Xs[c][r];
                lloss = fmaf(d, d, lloss);
                out[((size_t)(b*NC + c) * NHW) + hw0 + r] = va[q];
            }
        }
    }
    // deterministic block reduction of loss
#pragma unroll
    for (int off = 32; off > 0; off >>= 1)
        lloss += __shfl_down(lloss, off, 64);
    __syncthreads();
    if ((tid & 63) == 0) wsum[tid >> 6] = lloss;
    __syncthreads();
    if (tid == 0) partials[blk] = wsum[0] + wsum[1] + wsum[2] + wsum[3];
}

// ---------------- final loss reduction (deterministic) ----------------
__global__ void vq_loss_final(const float* __restrict__ partials, float* __restrict__ out_loss) {
    __shared__ float sdata[256];
    float s = 0.f;
    for (int i = threadIdx.x; i < NBLK; i += 256) s += partials[i];
    sdata[threadIdx.x] = s;
    __syncthreads();
    for (int off = 128; off > 0; off >>= 1) {
        if (threadIdx.x < off) sdata[threadIdx.x] += sdata[threadIdx.x + off];
        __syncthreads();
    }
    if (threadIdx.x == 0)
        out_loss[0] = 1.25f * sdata[0] / (float)NUMEL;
}

extern "C" void kernel_launch(void* const* d_in, const int* in_sizes, int n_in,
                              void* d_out, int out_size, void* d_ws, size_t ws_size,
                              hipStream_t stream) {
    const float* x   = (const float*)d_in[0];
    const float* emb = (const float*)d_in[1];
    float* out      = (float*)d_out;           // [NUMEL] quantized + [1] loss
    float* ws       = (float*)d_ws;
    float* partials = ws;                       // 2048 floats
    float* enorm    = ws + NBLK;                // 1024 floats

    hipLaunchKernelGGL(vq_enorm, dim3(NK / 256), dim3(256), 0, stream, emb, enorm);
    hipLaunchKernelGGL(vq_main, dim3(NBLK), dim3(256), 0, stream, x, emb, enorm, out, partials);
    hipLaunchKernelGGL(vq_loss_final, dim3(1), dim3(256), 0, stream, partials, out + NUMEL);
}

// Round 2
// 182.419 us; speedup vs baseline: 5.2136x; 5.2136x over previous
//
#include <hip/hip_runtime.h>

typedef float  f32x4  __attribute__((ext_vector_type(4)));
typedef __bf16 bf16x8 __attribute__((ext_vector_type(8)));

#define NB 32
#define NC 256
#define NHW 4096                  // 64*64
#define NN (NB*NHW)               // 131072 rows
#define NK 1024                   // codes
#define NUMEL ((size_t)NN*NC)     // 33554432
#define BM 128                    // rows per block
#define NBLK (NN/BM)              // 1024 blocks
#define NCHUNK 16                 // code chunks
#define CHUNK_ELEMS 16384         // 64 codes * 256 d (bf16 elems)

static __device__ __forceinline__ unsigned short f2bf(float f) {
    unsigned u = __builtin_bit_cast(unsigned, f);
    return (unsigned short)((u + 0x7fffu + ((u >> 16) & 1u)) >> 16);
}
static __device__ __forceinline__ float bf2f(unsigned short h) {
    unsigned u = ((unsigned)h) << 16;
    return __builtin_bit_cast(float, u);
}

#define GLDS(gsrc, ldst)                                                      \
    __builtin_amdgcn_global_load_lds(                                         \
        (const __attribute__((address_space(1))) unsigned int*)(gsrc),        \
        (__attribute__((address_space(3))) unsigned int*)(ldst), 16, 0, 0)

// ---------- prepack emb fp32 -> fragment-linear bf16 ----------
// off = ((((chunk*4+nt)*8+ds)*4+g)*16 + col)*8 + j
// code = chunk*64+nt*16+col ; k = ds*32+g*8+j
__global__ void vq_prepack(const float* __restrict__ emb, unsigned short* __restrict__ packed) {
    const int off = blockIdx.x * 256 + threadIdx.x;   // 0..262143
    const int j   = off & 7;
    const int col = (off >> 3) & 15;
    const int g   = (off >> 7) & 3;
    const int ds  = (off >> 9) & 7;
    const int nt  = (off >> 12) & 3;
    const int ch  = off >> 14;
    const int code = ch * 64 + nt * 16 + col;
    const int k    = ds * 32 + g * 8 + j;
    packed[off] = f2bf(emb[code * NC + k]);
}

// ---------- e_norm ----------
__global__ void vq_enorm(const float* __restrict__ emb, float* __restrict__ enorm) {
    int k = blockIdx.x * 256 + threadIdx.x;
    if (k >= NK) return;
    const float4* row = (const float4*)(emb + (size_t)k * NC);
    float s = 0.f;
#pragma unroll
    for (int i = 0; i < NC / 4; ++i) {
        float4 v = row[i];
        s = fmaf(v.x, v.x, fmaf(v.y, v.y, fmaf(v.z, v.z, fmaf(v.w, v.w, s))));
    }
    enorm[k] = s;
}

// ---------- main ----------
__global__ __launch_bounds__(512, 2)
void vq_main(const float* __restrict__ x, const float* __restrict__ emb,
             const unsigned short* __restrict__ packed, const float* __restrict__ enorm,
             float* __restrict__ out, float* __restrict__ partials)
{
    __shared__ __align__(16) unsigned short Xs[32768];        // 64 KiB frag-packed x
    __shared__ __align__(16) unsigned short Epk[2][CHUNK_ELEMS]; // 2x32 KiB E chunks
    __shared__ float enl[NK];                                  // 4 KiB
    __shared__ float wsum[8];

    const int tid  = threadIdx.x;
    const int blk  = blockIdx.x;
    const int b    = blk >> 5;                 // 32 tiles per image (4096/128)
    const int hwb  = (blk & 31) << 7;
    const int wv   = tid >> 6;
    const int lane = tid & 63;
    const int half = wv >> 2;                  // rows 0-63 or 64-127
    const int cg   = wv & 3;                   // 16-code group within chunk
    const int col  = lane & 15;
    const int g    = lane >> 4;

    // issue chunk-0 E stage as early as possible (hides under x staging)
#pragma unroll
    for (int i = 0; i < 4; ++i) {
        const unsigned short* gsrc = packed + (i * 8 + wv) * 512 + lane * 8;
        GLDS(gsrc, &Epk[0][(i * 8 + wv) * 512]);
    }

    // stage Xs: transpose [c][hw] -> frag-packed bf16
    {
        const int r4 = (tid & 31) << 2;
        const int c0 = tid >> 5;               // 0..15
#pragma unroll
        for (int it = 0; it < 16; ++it) {
            const int c = (c0 << 4) + it;
            const float4 v = *(const float4*)(x + ((size_t)(b * NC + c) * NHW) + hwb + r4);
            const int dsg = ((c >> 5) << 2) + ((c >> 3) & 3);   // ds*4+g
            const int j   = c & 7;
            const float va[4] = {v.x, v.y, v.z, v.w};
#pragma unroll
            for (int q = 0; q < 4; ++q) {
                const int r = r4 + q;
                const int off = ((r >> 6) << 14) + ((((r >> 4) & 3) << 5) + dsg) * 128 + ((r & 15) << 3) + j;
                Xs[off] = f2bf(va[q]);
            }
        }
    }
    enl[tid] = enorm[tid];
    enl[tid + 512] = enorm[tid + 512];
    __syncthreads();   // drains x loads + chunk-0 stage; Xs/enl visible

    // A fragments -> registers (rows = half*64 + mt*16 + col, k-octet g)
    bf16x8 afrag[4][8];
#pragma unroll
    for (int mt = 0; mt < 4; ++mt)
#pragma unroll
        for (int ds = 0; ds < 8; ++ds)
            afrag[mt][ds] = *(const bf16x8*)&Xs[(half << 14) + ((mt * 8 + ds) * 4 + g) * 128 + (col << 3)];

    float bestv[4][4];
    int   besti[4][4];
#pragma unroll
    for (int mt = 0; mt < 4; ++mt)
#pragma unroll
        for (int q = 0; q < 4; ++q) { bestv[mt][q] = 3.4e38f; besti[mt][q] = 0; }

    // ---- chunk loop: 2-phase double-buffered (counted vmcnt, raw barriers) ----
    for (int c = 0; c < NCHUNK; ++c) {
        const int cur = c & 1;
        if (c < NCHUNK - 1) {
            const int nb = cur ^ 1;
#pragma unroll
            for (int i = 0; i < 4; ++i) {
                const unsigned short* gsrc = packed + (c + 1) * CHUNK_ELEMS + (i * 8 + wv) * 512 + lane * 8;
                GLDS(gsrc, &Epk[nb][(i * 8 + wv) * 512]);
            }
            asm volatile("s_waitcnt vmcnt(4)" ::: "memory");
        } else {
            asm volatile("s_waitcnt vmcnt(0)" ::: "memory");
        }
        __builtin_amdgcn_s_barrier();

        f32x4 acc[4];
#pragma unroll
        for (int mt = 0; mt < 4; ++mt) acc[mt] = (f32x4){0.f, 0.f, 0.f, 0.f};

#pragma unroll
        for (int ds = 0; ds < 8; ++ds) {
            const bf16x8 bfrag = *(const bf16x8*)&Epk[cur][((cg * 8 + ds) * 4 + g) * 128 + (col << 3)];
#pragma unroll
            for (int mt = 0; mt < 4; ++mt)
                acc[mt] = __builtin_amdgcn_mfma_f32_16x16x32_bf16(afrag[mt][ds], bfrag, acc[mt], 0, 0, 0);
        }

        const int mycode = (c << 6) + (cg << 4) + col;
        const float en = enl[mycode];
#pragma unroll
        for (int mt = 0; mt < 4; ++mt)
#pragma unroll
            for (int q = 0; q < 4; ++q) {
                const float dist = fmaf(-2.f, acc[mt][q], en);   // ||e||^2 - 2 x.e
                if (dist < bestv[mt][q]) { bestv[mt][q] = dist; besti[mt][q] = mycode; }
            }
        __builtin_amdgcn_s_barrier();   // protect Epk[cur] before next-iter overwrite
    }

    // ---- cross-lane argmin over the 16 col-lanes ----
#pragma unroll
    for (int m = 1; m <= 8; m <<= 1) {
#pragma unroll
        for (int mt = 0; mt < 4; ++mt)
#pragma unroll
            for (int q = 0; q < 4; ++q) {
                const float ov = __shfl_xor(bestv[mt][q], m, 64);
                const int   oi = __shfl_xor(besti[mt][q], m, 64);
                if (ov < bestv[mt][q] || (ov == bestv[mt][q] && oi < besti[mt][q])) {
                    bestv[mt][q] = ov; besti[mt][q] = oi;
                }
            }
    }

    // ---- cross-wave argmin via LDS (overlay in Epk, now dead) ----
    float* redv = (float*)&Epk[0][0];                 // [4][128]
    int*   redi = (int*)((char*)&Epk[0][0] + 2048);   // [4][128]
    int*   widx = (int*)((char*)&Epk[0][0] + 4096);   // [128]
    if (col == 0) {
#pragma unroll
        for (int mt = 0; mt < 4; ++mt)
#pragma unroll
            for (int q = 0; q < 4; ++q) {
                const int row = (half << 6) + (mt << 4) + (g << 2) + q;
                redv[cg * 128 + row] = bestv[mt][q];
                redi[cg * 128 + row] = besti[mt][q];
            }
    }
    __syncthreads();
    if (tid < 128) {
        float bv = redv[tid]; int bi = redi[tid];
#pragma unroll
        for (int cgi = 1; cgi < 4; ++cgi) {
            const float v = redv[cgi * 128 + tid];
            const int   i = redi[cgi * 128 + tid];
            if (v < bv || (v == bv && i < bi)) { bv = v; bi = i; }
        }
        widx[tid] = bi;
    }
    __syncthreads();

    // ---- gather + output + loss (Xs still resident) ----
    float lloss = 0.f;
    {
        const int r4 = (tid & 31) << 2;
        const int c0 = tid >> 5;
        int wi[4];
#pragma unroll
        for (int q = 0; q < 4; ++q) wi[q] = widx[r4 + q];
#pragma unroll 4
        for (int cc = 0; cc < 16; ++cc) {
            const int c = (c0 << 4) + cc;
            float e[4];
#pragma unroll
            for (int q = 0; q < 4; ++q) e[q] = emb[(size_t)wi[q] * NC + c];
            float4 ov = {e[0], e[1], e[2], e[3]};
            *(float4*)(out + ((size_t)(b * NC + c) * NHW) + hwb + r4) = ov;
            const int dsg = ((c >> 5) << 2) + ((c >> 3) & 3);
            const int j   = c & 7;
#pragma unroll
            for (int q = 0; q < 4; ++q) {
                const int r = r4 + q;
                const int off = ((r >> 6) << 14) + ((((r >> 4) & 3) << 5) + dsg) * 128 + ((r & 15) << 3) + j;
                const float d = e[q] - bf2f(Xs[off]);
                lloss = fmaf(d, d, lloss);
            }
        }
    }
#pragma unroll
    for (int offd = 32; offd > 0; offd >>= 1)
        lloss += __shfl_down(lloss, offd, 64);
    if (lane == 0) wsum[wv] = lloss;
    __syncthreads();
    if (tid == 0) {
        float s = 0.f;
#pragma unroll
        for (int w = 0; w < 8; ++w) s += wsum[w];
        partials[blk] = s;
    }
}

// ---------- final loss reduction ----------
__global__ void vq_loss_final(const float* __restrict__ partials, float* __restrict__ out_loss) {
    __shared__ float sdata[256];
    float s = 0.f;
    for (int i = threadIdx.x; i < NBLK; i += 256) s += partials[i];
    sdata[threadIdx.x] = s;
    __syncthreads();
    for (int off = 128; off > 0; off >>= 1) {
        if (threadIdx.x < off) sdata[threadIdx.x] += sdata[threadIdx.x + off];
        __syncthreads();
    }
    if (threadIdx.x == 0)
        out_loss[0] = 1.25f * sdata[0] / (float)NUMEL;
}

extern "C" void kernel_launch(void* const* d_in, const int* in_sizes, int n_in,
                              void* d_out, int out_size, void* d_ws, size_t ws_size,
                              hipStream_t stream) {
    const float* x   = (const float*)d_in[0];
    const float* emb = (const float*)d_in[1];
    float* out = (float*)d_out;                       // [NUMEL] quantized + [1] loss
    char*  ws  = (char*)d_ws;
    float* partials = (float*)ws;                     // 1024 floats @ 0
    float* enorm    = (float*)(ws + 4096);            // 1024 floats
    unsigned short* packed = (unsigned short*)(ws + 8192);  // 512 KiB frag-packed emb

    hipLaunchKernelGGL(vq_prepack, dim3(NK * NC / 256), dim3(256), 0, stream, emb, packed);
    hipLaunchKernelGGL(vq_enorm, dim3(NK / 256), dim3(256), 0, stream, emb, enorm);
    hipLaunchKernelGGL(vq_main, dim3(NBLK), dim3(512), 0, stream, x, emb, packed, enorm, out, partials);
    hipLaunchKernelGGL(vq_loss_final, dim3(1), dim3(256), 0, stream, partials, out + NUMEL);
}

// Round 3
// 141.950 us; speedup vs baseline: 6.7000x; 1.2851x over previous
//
#include <hip/hip_runtime.h>

typedef float  f32x4  __attribute__((ext_vector_type(4)));
typedef __bf16 bf16x8 __attribute__((ext_vector_type(8)));
typedef unsigned short u16x8 __attribute__((ext_vector_type(8)));

#define NB 32
#define NC 256
#define NHW 4096                  // 64*64
#define NN (NB*NHW)               // 131072 rows
#define NK 1024                   // codes
#define NUMEL ((size_t)NN*NC)     // 33554432
#define BM 64                     // rows per block
#define NBLK (NN/BM)              // 2048 blocks
#define NCHUNK 32                 // 32 codes per chunk
#define CH_SHORTS 8192            // 32 codes * 256 k
#define QTS 258                   // padded Qt row stride (floats)

static __device__ __forceinline__ unsigned short f2bf(float f) {
    unsigned u = __builtin_bit_cast(unsigned, f);
    return (unsigned short)((u + 0x7fffu + ((u >> 16) & 1u)) >> 16);
}

#define GLDS(gsrc, ldst)                                                      \
    __builtin_amdgcn_global_load_lds(                                         \
        (const __attribute__((address_space(1))) unsigned int*)(gsrc),        \
        (__attribute__((address_space(3))) unsigned int*)(ldst), 16, 0, 0)

// ---------- prepack emb fp32 -> fragment-linear bf16 ----------
// off = [ch 32][nt 2][ds 8][g 4][col 16][j 8]
// code = ch*32 + nt*16 + col ; k = ds*32 + g*8 + j
__global__ void vq_prepack(const float* __restrict__ emb, unsigned short* __restrict__ packed) {
    const int off = blockIdx.x * 256 + threadIdx.x;   // 0..262143
    const int j   = off & 7;
    const int col = (off >> 3) & 15;
    const int g   = (off >> 7) & 3;
    const int ds  = (off >> 9) & 7;
    const int nt  = (off >> 12) & 1;
    const int ch  = off >> 13;
    const int code = ch * 32 + nt * 16 + col;
    const int k    = ds * 32 + g * 8 + j;
    packed[off] = f2bf(emb[code * NC + k]);
}

// ---------- e_norm ----------
__global__ void vq_enorm(const float* __restrict__ emb, float* __restrict__ enorm) {
    int k = blockIdx.x * 256 + threadIdx.x;
    if (k >= NK) return;
    const float4* row = (const float4*)(emb + (size_t)k * NC);
    float s = 0.f;
#pragma unroll
    for (int i = 0; i < NC / 4; ++i) {
        float4 v = row[i];
        s = fmaf(v.x, v.x, fmaf(v.y, v.y, fmaf(v.z, v.z, fmaf(v.w, v.w, s))));
    }
    enorm[k] = s;
}

// ---------- main ----------
__global__ __launch_bounds__(512, 4)
void vq_main(const float* __restrict__ x, const float* __restrict__ emb,
             const unsigned short* __restrict__ packed, const float* __restrict__ enorm_g,
             float* __restrict__ out, float* __restrict__ partials)
{
    __shared__ __align__(16) char LDS[71680];
    unsigned short* Xb  = (unsigned short*)LDS;            // [c 256][r 64] bf16, 32 KiB
    unsigned short* Epk = (unsigned short*)(LDS + 32768);  // [2][8192] bf16, 32 KiB
    float*          enl = (float*)(LDS + 65536);           // [1024], 4 KiB
    float*          redv = (float*)(LDS + 69632);          // [2][64]
    int*            redi = (int*)(LDS + 70144);            // [2][64]
    int*            widx = (int*)(LDS + 70656);            // [64]
    float*          wsum = (float*)(LDS + 70912);          // [8]
    float*          Qt  = (float*)LDS;                     // [64][258] fp32 overlay (66048 B, dead Xb/Epk/enl)

    const int tid  = threadIdx.x;
    const int blk  = blockIdx.x;
    const int b    = blk >> 6;                 // 64 tiles of 64 hw per image
    const int hw0  = (blk & 63) << 6;
    const int wv   = tid >> 6;
    const int lane = tid & 63;
    const int rh   = wv >> 1;                  // row quarter (16 rows)
    const int nt   = wv & 1;                   // 16-code group within chunk
    const int col  = lane & 15;
    const int g    = lane >> 4;

    // prefetch chunk 0 (2 GLDS per wave, 16 total = 16 KiB)
#pragma unroll
    for (int i2 = 0; i2 < 2; ++i2) {
        const int i = wv * 2 + i2;
        GLDS(packed + i * 512 + lane * 8, Epk + i * 512 + lane * 8);
    }

    // stage x -> Xb[c][r] bf16 (coalesced loads, contiguous conflict-free ushort4 stores) + sum x^2
    float xsq = 0.f;
    {
        const int r4 = (tid & 15) << 2;
        const int cb = tid >> 4;               // 0..31
#pragma unroll
        for (int it = 0; it < 8; ++it) {
            const int c = cb + (it << 5);
            const float4 v = *(const float4*)(x + (size_t)(b * NC + c) * NHW + hw0 + r4);
            xsq = fmaf(v.x, v.x, fmaf(v.y, v.y, fmaf(v.z, v.z, fmaf(v.w, v.w, xsq))));
            ushort4 h = {f2bf(v.x), f2bf(v.y), f2bf(v.z), f2bf(v.w)};
            *(ushort4*)&Xb[c * 64 + r4] = h;
        }
    }
    enl[tid]       = enorm_g[tid];
    enl[tid + 512] = enorm_g[tid + 512];
#pragma unroll
    for (int o = 32; o > 0; o >>= 1) xsq += __shfl_down(xsq, o, 64);
    if (lane == 0) wsum[wv] = xsq;
    __syncthreads();   // drains x stores + chunk-0 GLDS; Xb/enl/Epk[0] visible

    // A fragments -> registers: row = rh*16 + col, k = ds*32 + g*8 + j
    bf16x8 af[8];
    {
        const int arow = (rh << 4) + col;
#pragma unroll
        for (int ds = 0; ds < 8; ++ds) {
            u16x8 t;
#pragma unroll
            for (int jj = 0; jj < 8; ++jj)
                t[jj] = Xb[(ds * 32 + g * 8 + jj) * 64 + arow];
            af[ds] = __builtin_bit_cast(bf16x8, t);
        }
    }

    float bestv[4];
    int   besti[4];
#pragma unroll
    for (int q = 0; q < 4; ++q) { bestv[q] = 3.4e38f; besti[q] = 0; }

    // ---- chunk loop: counted-vmcnt double buffer ----
    for (int ch = 0; ch < NCHUNK; ++ch) {
        const int cur = ch & 1;
        if (ch < NCHUNK - 1) {
#pragma unroll
            for (int i2 = 0; i2 < 2; ++i2) {
                const int i = wv * 2 + i2;
                GLDS(packed + (ch + 1) * CH_SHORTS + i * 512 + lane * 8,
                     Epk + (cur ^ 1) * CH_SHORTS + i * 512 + lane * 8);
            }
            asm volatile("s_waitcnt vmcnt(2)" ::: "memory");
        } else {
            asm volatile("s_waitcnt vmcnt(0)" ::: "memory");
        }
        __builtin_amdgcn_s_barrier();

        const unsigned short* eb = Epk + cur * CH_SHORTS + nt * 4096 + g * 128 + (col << 3);
        f32x4 a0 = {0.f, 0.f, 0.f, 0.f};
        f32x4 a1 = {0.f, 0.f, 0.f, 0.f};
#pragma unroll
        for (int ds = 0; ds < 8; ds += 2) {
            a0 = __builtin_amdgcn_mfma_f32_16x16x32_bf16(af[ds],     *(const bf16x8*)(eb + ds * 512),       a0, 0, 0, 0);
            a1 = __builtin_amdgcn_mfma_f32_16x16x32_bf16(af[ds + 1], *(const bf16x8*)(eb + (ds + 1) * 512), a1, 0, 0, 0);
        }

        const int mycode = (ch << 5) + (nt << 4) + col;
        const float en = enl[mycode];
#pragma unroll
        for (int q = 0; q < 4; ++q) {
            const float dist = fmaf(-2.f, a0[q] + a1[q], en);   // ||e||^2 - 2 x.e
            if (dist < bestv[q]) { bestv[q] = dist; besti[q] = mycode; }
        }
        __builtin_amdgcn_s_barrier();   // Epk[cur] free for next prefetch
    }

    // ---- cross-lane argmin over the 16 col-lanes ----
#pragma unroll
    for (int m = 1; m <= 8; m <<= 1) {
#pragma unroll
        for (int q = 0; q < 4; ++q) {
            const float ov = __shfl_xor(bestv[q], m, 64);
            const int   oi = __shfl_xor(besti[q], m, 64);
            if (ov < bestv[q] || (ov == bestv[q] && oi < besti[q])) { bestv[q] = ov; besti[q] = oi; }
        }
    }

    // ---- cross-wave (nt) argmin + loss partial ----
    if (col == 0) {
#pragma unroll
        for (int q = 0; q < 4; ++q) {
            const int r = (rh << 4) + (g << 2) + q;
            redv[nt * 64 + r] = bestv[q];
            redi[nt * 64 + r] = besti[q];
        }
    }
    __syncthreads();
    if (tid < 64) {
        float bv = redv[tid]; int bi = redi[tid];
        const float v1 = redv[64 + tid]; const int i1 = redi[64 + tid];
        if (v1 < bv || (v1 == bv && i1 < bi)) { bv = v1; bi = i1; }
        widx[tid] = bi;
        float bsum = bv;
#pragma unroll
        for (int o = 32; o > 0; o >>= 1) bsum += __shfl_down(bsum, o, 64);
        if (tid == 0) {
            float s = bsum;   // sum of min-dists = sum(||e||^2 - 2 x.e)
#pragma unroll
            for (int w = 0; w < 8; ++w) s += wsum[w];   // + sum(x^2)
            partials[blk] = s;                           // = sum ||e - x||^2
        }
    }
    __syncthreads();

    // ---- gather e-rows coalesced -> Qt fp32 (exact), then transposed write-out ----
#pragma unroll
    for (int rr = 0; rr < 8; ++rr) {
        const int r  = (wv << 3) + rr;
        const int ki = widx[r];                         // wave-uniform LDS broadcast
        const float4 ev = *(const float4*)(emb + (size_t)ki * NC + (lane << 2));
        const int base = r * QTS + (lane << 2);
        *(float2*)&Qt[base]     = {ev.x, ev.y};
        *(float2*)&Qt[base + 2] = {ev.z, ev.w};
    }
    __syncthreads();
#pragma unroll
    for (int cc = 0; cc < 32; ++cc) {
        const int c = (wv << 5) + cc;
        out[(size_t)(b * NC + c) * NHW + hw0 + lane] = Qt[lane * QTS + c];
    }
}

// ---------- final loss reduction ----------
__global__ void vq_loss_final(const float* __restrict__ partials, float* __restrict__ out_loss) {
    __shared__ float sdata[256];
    float s = 0.f;
    for (int i = threadIdx.x; i < NBLK; i += 256) s += partials[i];
    sdata[threadIdx.x] = s;
    __syncthreads();
    for (int off = 128; off > 0; off >>= 1) {
        if (threadIdx.x < off) sdata[threadIdx.x] += sdata[threadIdx.x + off];
        __syncthreads();
    }
    if (threadIdx.x == 0)
        out_loss[0] = 1.25f * sdata[0] / (float)NUMEL;
}

extern "C" void kernel_launch(void* const* d_in, const int* in_sizes, int n_in,
                              void* d_out, int out_size, void* d_ws, size_t ws_size,
                              hipStream_t stream) {
    const float* x   = (const float*)d_in[0];
    const float* emb = (const float*)d_in[1];
    float* out = (float*)d_out;                              // [NUMEL] quantized + [1] loss
    char*  ws  = (char*)d_ws;
    float* partials = (float*)ws;                            // 2048 floats @ 0
    float* enorm    = (float*)(ws + 8192);                   // 1024 floats
    unsigned short* packed = (unsigned short*)(ws + 12288);  // 512 KiB frag-packed emb

    hipLaunchKernelGGL(vq_prepack, dim3(NK * NC / 256), dim3(256), 0, stream, emb, packed);
    hipLaunchKernelGGL(vq_enorm, dim3(NK / 256), dim3(256), 0, stream, emb, enorm);
    hipLaunchKernelGGL(vq_main, dim3(NBLK), dim3(512), 0, stream, x, emb, packed, enorm, out, partials);
    hipLaunchKernelGGL(vq_loss_final, dim3(1), dim3(256), 0, stream, partials, out + NUMEL);
}